// Round 9
// baseline (2670.982 us; speedup 1.0000x reference)
//
#include <hip/hip_runtime.h>
#include <stdint.h>

// Problem constants (match reference)
#define B_ROWS 16384
#define V_DIM  1024
#define H_DIM  1024
#define KB     1152   // padded K: 1024 state + 64 h1-tail + 64 ZERO pad (mult of 128)
#define C_DIM  64
#define P_COLS 4096   // 2*(V+H)
#define K_STEPS 25

#define FP8_ONE 0x38  // e4m3fn 1.0
#define FP8_NEG1 0xB8 // e4m3fn -1.0

typedef float f32x4 __attribute__((ext_vector_type(4)));
typedef int   v8i   __attribute__((ext_vector_type(8)));

// ---------------------------------------------------------------------------
// RNG. hash32 (lowbias32) seeds a per-thread LCG; epilogue draws are LCG
// high-16 bits. Deterministic per (thread, tag); loss is RNG-invariant
// (R1-R8: absmax == fp8-quantization error only).
// ---------------------------------------------------------------------------
__device__ __forceinline__ uint32_t hash32(uint32_t idx, uint32_t tagmix) {
    uint32_t x = idx * 0x9E3779B9u ^ tagmix;
    x ^= x >> 16; x *= 0x7FEB352Du;
    x ^= x >> 15; x *= 0x846CA68Bu;
    x ^= x >> 16;
    return x;
}

// async global->LDS, 16B per lane. LDS dst = wave-uniform base + lane*16.
__device__ __forceinline__ void load_lds16(const void* g, void* l) {
    __builtin_amdgcn_global_load_lds(
        (__attribute__((address_space(1))) void*)(uintptr_t)(g),
        (__attribute__((address_space(3))) void*)(l),
        16, 0, 0);
}

__device__ __forceinline__ float softplus_f(float x) {
    return fmaxf(x, 0.0f) + log1pf(__expf(-fabsf(x)));
}

__device__ __forceinline__ uint8_t f2fp8(float x) {
    int p = __builtin_amdgcn_cvt_pk_fp8_f32(x, 0.0f, 0, false);
    return (uint8_t)(p & 0xFF);
}

#define NEG_L2E (-1.4426950408889634f)

// ---------------------------------------------------------------------------
// fp8 GEMM C = A (MxK) * Bt^T (Bt NxK row-major), via
// mfma_scale_f32_16x16x128_f8f6f4 with unit scales.
// R9 = R8 structure (256 thr, 4 waves of 64x32, BM=128 x BN=64 x BK=128,
// XCD swizzle, LCG epilogue) with ONE change:
//   B-fragments are loaded DIRECTLY FROM GLOBAL (L2-resident shared W-slab,
//   32 contiguous B/lane -> two dwordx4, no swizzle, no LDS round-trip).
//   R8 cycle stack showed the LDS pipe as the tallest pole (reads 11.5us +
//   writes 5.6us + conflicts 5.8us vs MFMA floor 8.3us per 28us dispatch);
//   this cuts LDS reads and writes by 1/3 and rides the VMEM/L2 pipe, which
//   overlaps with LDS (m114). Occupancy unchanged (LDS 24->16 KB).
// A staging unchanged: global_load_lds w/ 16B slots XOR-swizzled by row&7.
// MODE 0: out_s = bernoulli(sigmoid(C + cvec)) fp8 {0,0x38}, row-stride KB
// MODE 1: atomicAdd(out_f, scale * sum(softplus(C + cvec)))
// MODE 2: out_f[row*N + col] = C   (raw fp32 store, no cvec)
// ---------------------------------------------------------------------------
template <int MODE>
__global__ __launch_bounds__(256, 5) void gemm_ep(
    const uint8_t* __restrict__ A, const uint8_t* __restrict__ Bt,
    const float* __restrict__ cvec, uint8_t* __restrict__ out_s,
    float* __restrict__ out_f, int M, int N, int K,
    uint32_t tag, float scale)
{
    constexpr int BM = 128, BN = 64, BK = 128;
    __shared__ __align__(16) uint8_t sA[BM * BK];   // 16 KB (A only)

    const int tid  = threadIdx.x;
    const int wave = tid >> 6;
    const int lane = tid & 63;
    // XCD-aware swizzle (grid = 128 * n_blocks, 1D)
    const int bid   = blockIdx.x;
    const int m_idx = ((bid & 7) << 4) | ((bid >> 3) & 15);
    const int n_idx = bid >> 7;
    const int m0 = m_idx * BM;
    const int n0 = n_idx * BN;
    const int wr = (wave >> 1) * 64;   // wave row offset (0/64)
    const int wc = (wave & 1) * 32;    // wave col offset (0/32)
    const int cl   = lane & 15;
    const int quad = lane >> 4;

    // A staging: 16 chunks of (8 rows x 128 B); wave w loads chunks [4w,4w+4).
    // Lane covers row lane>>3, 16B slot XOR-swizzled by row&7.
    const int lrow8 = lane >> 3;
    const int lcol  = ((lane & 7) ^ lrow8) << 4;
    const uint8_t* gp[4];
    uint8_t*       lp[4];
#pragma unroll
    for (int i = 0; i < 4; ++i) {
        int c = wave * 4 + i;
        gp[i] = A + (size_t)(m0 + c * 8 + lrow8) * K + lcol;
        lp[i] = sA + c * 8 * BK;
    }

    // B-fragment global offsets: Bt[n0+wc+ni*16+cl][kt + quad*32 .. +32)
    const size_t boff0 = (size_t)(n0 + wc + cl) * K + quad * 32;
    const size_t boff1 = (size_t)(n0 + wc + 16 + cl) * K + quad * 32;

    f32x4 acc[4][2] = {};
    union F8 { int4 h[2]; v8i v; };
    const int xr = cl & 7;
    const int p0 = ((2 * quad) ^ xr) << 4;
    const int p1 = ((2 * quad + 1) ^ xr) << 4;

    for (int kt = 0; kt < K; kt += BK) {
#pragma unroll
        for (int i = 0; i < 4; ++i) load_lds16(gp[i] + kt, lp[i]);
        // B frags issue while A staging is in flight; the pre-barrier
        // vmcnt(0) drain covers both.
        const uint8_t* bp = Bt + kt;
        F8 fb0, fb1;
        fb0.h[0] = *(const int4*)(bp + boff0);
        fb0.h[1] = *(const int4*)(bp + boff0 + 16);
        fb1.h[0] = *(const int4*)(bp + boff1);
        fb1.h[1] = *(const int4*)(bp + boff1 + 16);
        __syncthreads();

        v8i af[4];
#pragma unroll
        for (int mi = 0; mi < 4; ++mi) {
            const uint8_t* rp = sA + (wr + mi * 16 + cl) * BK;
            F8 f; f.h[0] = *(const int4*)(rp + p0); f.h[1] = *(const int4*)(rp + p1);
            af[mi] = f.v;
        }
#pragma unroll
        for (int mi = 0; mi < 4; ++mi) {
            acc[mi][0] = __builtin_amdgcn_mfma_scale_f32_16x16x128_f8f6f4(
                af[mi], fb0.v, acc[mi][0], 0, 0, 0, 0x7F7F7F7F, 0, 0x7F7F7F7F);
            acc[mi][1] = __builtin_amdgcn_mfma_scale_f32_16x16x128_f8f6f4(
                af[mi], fb1.v, acc[mi][1], 0, 0, 0, 0x7F7F7F7F, 0, 0x7F7F7F7F);
        }
        __syncthreads();
    }

    // Epilogue. C/D layout: col = lane&15, row = quad*4 + reg (per 16x16 tile)
    const int row_base = m0 + wr + quad * 4;
    const int col_base = n0 + wc + cl;

    if (MODE == 0) {
        const uint32_t tagmix = tag * 0x85EBCA6Bu + 0xC2B2AE35u;
        uint32_t s = hash32((uint32_t)(bid * 256 + tid), tagmix);  // LCG seed
        float ccv[2];
#pragma unroll
        for (int ni = 0; ni < 2; ++ni)
            ccv[ni] = cvec[col_base + ni * 16] * NEG_L2E;
#pragma unroll
        for (int mi = 0; mi < 4; ++mi) {
#pragma unroll
            for (int ni = 0; ni < 2; ++ni) {
                int col = col_base + ni * 16;
#pragma unroll
                for (int r = 0; r < 4; ++r) {
                    int row = row_base + mi * 16 + r;
                    // u < sigmoid(x)  <=>  u16*(1+e^-x) < 65536
                    float t = fmaf(acc[mi][ni][r], NEG_L2E, ccv[ni]);
                    float e = __builtin_amdgcn_exp2f(t);
                    s = s * 1664525u + 1013904223u;
                    float uf = (float)(s >> 16);
                    float prod = uf * (1.0f + e);
                    out_s[(size_t)row * KB + col] =
                        (prod < 65536.0f) ? (uint8_t)FP8_ONE : (uint8_t)0;
                }
            }
        }
    } else if (MODE == 1) {
        float cv[2];
#pragma unroll
        for (int ni = 0; ni < 2; ++ni) cv[ni] = cvec[col_base + ni * 16];
        float local = 0.0f;
#pragma unroll
        for (int mi = 0; mi < 4; ++mi)
#pragma unroll
            for (int ni = 0; ni < 2; ++ni)
#pragma unroll
                for (int r = 0; r < 4; ++r)
                    local += softplus_f(acc[mi][ni][r] + cv[ni]);
        local *= scale;
        for (int off = 32; off > 0; off >>= 1)
            local += __shfl_down(local, off, 64);
        __shared__ float wsum[4];
        if (lane == 0) wsum[wave] = local;
        __syncthreads();
        if (tid == 0)
            atomicAdd(out_f, wsum[0] + wsum[1] + wsum[2] + wsum[3]);
    } else {
#pragma unroll
        for (int mi = 0; mi < 4; ++mi)
#pragma unroll
            for (int ni = 0; ni < 2; ++ni)
#pragma unroll
                for (int r = 0; r < 4; ++r) {
                    int row = row_base + mi * 16 + r;
                    int col = col_base + ni * 16;
                    out_f[(size_t)row * N + col] = acc[mi][ni][r];
                }
    }
}

// ---------------------------------------------------------------------------
// W (VxH fp32) -> fp8 B-operands (row stride KB):
//   Btv[n][k] = W[n][k]  (v-GEMM)    Bth[n][k] = W[k][n]  (h-GEMM)
// ---------------------------------------------------------------------------
__global__ void wpack_kernel(const float* __restrict__ W,
                             uint8_t* __restrict__ Btv, uint8_t* __restrict__ Bth) {
    __shared__ float tile[32][33];
    int bx = blockIdx.x * 32, by = blockIdx.y * 32;
    int tx = threadIdx.x & 31, ty = threadIdx.x >> 5;
#pragma unroll
    for (int r = ty; r < 32; r += 8) {
        float v = W[(size_t)(by + r) * H_DIM + bx + tx];
        Btv[(size_t)(by + r) * KB + bx + tx] = f2fp8(v);
        tile[r][tx] = v;
    }
    __syncthreads();
#pragma unroll
    for (int r = ty; r < 32; r += 8)
        Bth[(size_t)(bx + r) * KB + by + tx] = f2fp8(tile[tx][r]);
}

// Tail cols [1024,1152) of Btv/Bth: rank-64 modulation factors + zero pad.
// Also fills BtP (the bdot-replacement B operand, 128 rows x KB):
//   BtP[k'][j] = Whb[k'][j] (k'<64), BtP[64][j] = bhat[j], rows 65..127 = 0
__global__ void wtail_kernel(const float* __restrict__ W2, const float* __restrict__ b,
                             const float* __restrict__ c, const float* __restrict__ b2,
                             uint8_t* __restrict__ Btv, uint8_t* __restrict__ Bth,
                             uint8_t* __restrict__ BtP) {
    int gid = blockIdx.x * 256 + threadIdx.x;   // 1024 * 128
    int n = gid >> 7, kp = gid & 127;
    if (kp < 64) {
        float wc = W2[(size_t)kp * P_COLS + 2048 + n] * c[n] + W2[(size_t)kp * P_COLS + 3072 + n];
        float wb = W2[(size_t)kp * P_COLS + n] * b[n]        + W2[(size_t)kp * P_COLS + 1024 + n];
        Bth[(size_t)n * KB + 1024 + kp] = f2fp8(wc);
        Btv[(size_t)n * KB + 1024 + kp] = f2fp8(wb);
        BtP[(size_t)kp * KB + n] = f2fp8(wb);
    } else {
        Bth[(size_t)n * KB + 1024 + kp] = 0;    // zero pad
        Btv[(size_t)n * KB + 1024 + kp] = 0;
        if (kp == 64) {
            float bh = b[n] * (1.0f + b2[n]) + b2[1024 + n];
            BtP[(size_t)64 * KB + n] = f2fp8(bh);
        } else {
            BtP[(size_t)kp * KB + n] = 0;
        }
    }
}

// Row-independent modulation constants (fp32, used as GEMM cvec):
__global__ void hatvec_kernel(const float* __restrict__ b, const float* __restrict__ c,
                              const float* __restrict__ b2,
                              float* __restrict__ bhat, float* __restrict__ chat) {
    int n = blockIdx.x * 256 + threadIdx.x;
    bhat[n] = b[n] * (1.0f + b2[n]) + b2[1024 + n];
    chat[n] = c[n] * (1.0f + b2[2048 + n]) + b2[3072 + n];
}

// h1 = tanh(cond @ W1 + b1); fp32 h1f + fp8 copies into tail cols of buffers.
__global__ void h1_kernel(const float* __restrict__ cond, const float* __restrict__ W1,
                          const float* __restrict__ b1, float* __restrict__ h1f,
                          uint8_t* __restrict__ vbuf, uint8_t* __restrict__ hbuf,
                          uint8_t* __restrict__ vdbuf) {
    int row = blockIdx.x * 4 + (threadIdx.x >> 6);
    int j   = threadIdx.x & 63;
    const float* cr = cond + (size_t)row * C_DIM;
    float s = b1[j];
#pragma unroll 8
    for (int k = 0; k < C_DIM; ++k) s = fmaf(cr[k], W1[k * 64 + j], s);
    float t = tanhf(s);
    h1f[(size_t)row * 64 + j] = t;
    size_t o = (size_t)row * KB + 1024 + j;
    uint8_t tb = f2fp8(t);
    vbuf[o] = tb; hbuf[o] = tb; vdbuf[o] = tb;
}

// v_start ~ Bern(0.5) into vbuf cols [0,1024)
__global__ void initv_kernel(uint8_t* __restrict__ v, uint32_t tag) {
    uint32_t g = (blockIdx.x * 256 + threadIdx.x) * 4;
    uint32_t row = g >> 10, col = g & 1023;
    uint32_t tagmix = tag * 0x85EBCA6Bu + 0xC2B2AE35u;
    uint32_t w = 0;
#pragma unroll
    for (int e = 0; e < 4; ++e)
        if (hash32(g + e, tagmix) & 0x80000000u)
            w |= (uint32_t)FP8_ONE << (8 * e);
    *(uint32_t*)(v + (size_t)row * KB + col) = w;
}

// v_data (fp32 0/1) -> vdbuf cols [0,1024), fp8 exact
__global__ void cast_kernel(const float* __restrict__ src, uint8_t* __restrict__ dst) {
    uint32_t g = (blockIdx.x * 256 + threadIdx.x) * 4;
    uint32_t row = g >> 10, col = g & 1023;
    f32x4 s = *(const f32x4*)(src + g);
    uint32_t w = 0;
#pragma unroll
    for (int e = 0; e < 4; ++e)
        if (s[e] >= 0.5f) w |= (uint32_t)FP8_ONE << (8 * e);
    *(uint32_t*)(dst + (size_t)row * KB + col) = w;
}

// T = vm - vd in fp8, written IN-PLACE over vd (tails cancel to exact 0).
__global__ void tdiff_kernel(uint8_t* __restrict__ vd, const uint8_t* __restrict__ vm) {
    size_t g = ((size_t)blockIdx.x * 256 + threadIdx.x) * 4;
    uint32_t a = *(const uint32_t*)(vm + g);
    uint32_t d = *(const uint32_t*)(vd + g);
    uint32_t t = 0;
#pragma unroll
    for (int e = 0; e < 4; ++e) {
        uint32_t vb = (a >> (8 * e)) & 0xFF, db = (d >> (8 * e)) & 0xFF;
        if (vb != db) t |= (vb ? (uint32_t)FP8_ONE : (uint32_t)FP8_NEG1) << (8 * e);
    }
    *(uint32_t*)(vd + g) = t;
}

// out += scale * sum_i [ P[i][64] + sum_k h1f[i][k] * P[i][k] ]
__global__ __launch_bounds__(256) void preduce_kernel(
    const float* __restrict__ P, const float* __restrict__ h1f,
    float* __restrict__ out, float scale) {
    int row = blockIdx.x * 256 + threadIdx.x;
    const f32x4* pr = (const f32x4*)(P + (size_t)row * 128);
    const f32x4* hr = (const f32x4*)(h1f + (size_t)row * 64);
    float local = P[(size_t)row * 128 + 64];
#pragma unroll
    for (int q = 0; q < 16; ++q) {
        f32x4 pv = pr[q], hv = hr[q];
#pragma unroll
        for (int e = 0; e < 4; ++e) local = fmaf(hv[e], pv[e], local);
    }
    local *= scale;
    for (int off = 32; off > 0; off >>= 1)
        local += __shfl_down(local, off, 64);
    __shared__ float wsum[4];
    int lane = threadIdx.x & 63, wave = threadIdx.x >> 6;
    if (lane == 0) wsum[wave] = local;
    __syncthreads();
    if (threadIdx.x == 0)
        atomicAdd(out, wsum[0] + wsum[1] + wsum[2] + wsum[3]);
}

// ---------------------------------------------------------------------------
extern "C" void kernel_launch(void* const* d_in, const int* in_sizes, int n_in,
                              void* d_out, int out_size, void* d_ws, size_t ws_size,
                              hipStream_t stream) {
    (void)in_sizes; (void)n_in; (void)out_size; (void)ws_size;
    const float* v_data = (const float*)d_in[0];
    const float* cond   = (const float*)d_in[1];
    const float* W      = (const float*)d_in[2];
    const float* b      = (const float*)d_in[3];
    const float* c      = (const float*)d_in[4];
    const float* W1     = (const float*)d_in[5];
    const float* b1     = (const float*)d_in[6];
    const float* W2     = (const float*)d_in[7];
    const float* b2     = (const float*)d_in[8];
    float* out = (float*)d_out;
    char*  ws  = (char*)d_ws;

    const size_t MB = 1024 * 1024;
    uint8_t* Btv  = (uint8_t*)(ws + 0 * MB);    // 1024 x KB fp8
    uint8_t* Bth  = (uint8_t*)(ws + 2 * MB);    // 1024 x KB fp8
    uint8_t* BtP  = (uint8_t*)(ws + 4 * MB);    // 128 x KB fp8 (144 KB)
    float*   h1f  = (float*)  (ws + 5 * MB);    // B x 64 fp32 (4 MB)
    float*   bhat = (float*)  (ws + 9 * MB);
    float*   chat = (float*)  (ws + 10 * MB);
    float*   Pbuf = (float*)  (ws + 11 * MB);   // B x 128 fp32 (8 MB)
    uint8_t* vbuf = (uint8_t*)(ws + 20 * MB);   // B x KB fp8 (18.9 MB)
    uint8_t* hbuf = (uint8_t*)(ws + 40 * MB);
    uint8_t* vdbuf= (uint8_t*)(ws + 60 * MB);
    // total ~79 MB

    hipMemsetAsync(d_out, 0, sizeof(float), stream);
    hipMemsetAsync(BtP, 0, (size_t)128 * KB, stream);  // tail cols + zero rows

    h1_kernel<<<B_ROWS / 4, 256, 0, stream>>>(cond, W1, b1, h1f, vbuf, hbuf, vdbuf);
    wpack_kernel<<<dim3(32, 32), 256, 0, stream>>>(W, Btv, Bth);
    wtail_kernel<<<(1024 * 128) / 256, 256, 0, stream>>>(W2, b, c, b2, Btv, Bth, BtP);
    hatvec_kernel<<<4, 256, 0, stream>>>(b, c, b2, bhat, chat);
    initv_kernel<<<(B_ROWS * 1024) / 1024, 256, 0, stream>>>(vbuf, 7u);
    cast_kernel<<<(B_ROWS * 1024) / 1024, 256, 0, stream>>>(v_data, vdbuf);

    const int ggrid = 2048;               // 128 m-blocks x 16 n-blocks, 1D+swizzle
    const float invB = 1.0f / (float)B_ROWS;

    for (int k = 0; k < K_STEPS; ++k) {
        gemm_ep<0><<<ggrid, 256, 0, stream>>>(vbuf, Bth, chat, hbuf, nullptr,
                                              B_ROWS, H_DIM, KB,
                                              100u + 2u * (uint32_t)k, 0.0f);
        gemm_ep<0><<<ggrid, 256, 0, stream>>>(hbuf, Btv, bhat, vbuf, nullptr,
                                              B_ROWS, V_DIM, KB,
                                              101u + 2u * (uint32_t)k, 0.0f);
    }

    // loss*B = sum softplus(vm@W + c_mod) - sum softplus(vd@W + c_mod)
    //          + sum (vm - vd)*b_mod      (rank-64 factored, GEMM-shaped)
    gemm_ep<1><<<ggrid, 256, 0, stream>>>(vbuf, Bth, chat, nullptr, out,
                                          B_ROWS, H_DIM, KB, 0u, invB);
    gemm_ep<1><<<ggrid, 256, 0, stream>>>(vdbuf, Bth, chat, nullptr, out,
                                          B_ROWS, H_DIM, KB, 1u, -invB);
    tdiff_kernel<<<(B_ROWS * KB) / 1024, 256, 0, stream>>>(vdbuf, vbuf);
    gemm_ep<2><<<256, 256, 0, stream>>>(vdbuf, BtP, nullptr, nullptr, Pbuf,
                                        B_ROWS, 128, KB, 0u, 0.0f);
    preduce_kernel<<<B_ROWS / 256, 256, 0, stream>>>(Pbuf, h1f, out, invB);
}

// Round 10
// 2031.392 us; speedup vs baseline: 1.3149x; 1.3149x over previous
//
#include <hip/hip_runtime.h>
#include <stdint.h>

// Problem constants (match reference)
#define B_ROWS 16384
#define V_DIM  1024
#define H_DIM  1024
#define KB     1152   // padded K: 1024 state + 64 h1-tail + 64 ZERO pad (mult of 128)
#define C_DIM  64
#define P_COLS 4096   // 2*(V+H)
#define K_STEPS 25

#define FP8_ONE 0x38  // e4m3fn 1.0
#define FP8_NEG1 0xB8 // e4m3fn -1.0

typedef float f32x4 __attribute__((ext_vector_type(4)));
typedef int   v8i   __attribute__((ext_vector_type(8)));

// ---------------------------------------------------------------------------
// RNG. hash32 (lowbias32) seeds a per-thread LCG; epilogue draws are LCG
// high-16 bits. Deterministic per (thread, tag); loss is RNG-invariant
// (R1-R9: absmax == fp8-quantization error only).
// ---------------------------------------------------------------------------
__device__ __forceinline__ uint32_t hash32(uint32_t idx, uint32_t tagmix) {
    uint32_t x = idx * 0x9E3779B9u ^ tagmix;
    x ^= x >> 16; x *= 0x7FEB352Du;
    x ^= x >> 15; x *= 0x846CA68Bu;
    x ^= x >> 16;
    return x;
}

// async global->LDS, 16B per lane. LDS dst = wave-uniform base + lane*16.
__device__ __forceinline__ void load_lds16(const void* g, void* l) {
    __builtin_amdgcn_global_load_lds(
        (__attribute__((address_space(1))) void*)(uintptr_t)(g),
        (__attribute__((address_space(3))) void*)(l),
        16, 0, 0);
}

__device__ __forceinline__ float softplus_f(float x) {
    return fmaxf(x, 0.0f) + log1pf(__expf(-fabsf(x)));
}

__device__ __forceinline__ uint8_t f2fp8(float x) {
    int p = __builtin_amdgcn_cvt_pk_fp8_f32(x, 0.0f, 0, false);
    return (uint8_t)(p & 0xFF);
}

#define NEG_L2E (-1.4426950408889634f)

// ---------------------------------------------------------------------------
// fp8 GEMM C = A (MxKB) * Bt^T (Bt NxKB row-major), K fixed = KB, via
// mfma_scale_f32_16x16x128_f8f6f4 with unit scales.
// R10: B back in LDS (R9's global-B frags serialized scattered L2 latency
// into the pre-barrier vmcnt drain every iter — reverted). Tile now
// BM=128 x BN=128 x BK=128, 256 thr / 4 waves, WAVE-TILE 64x64 (acc 4x4):
//  - LDS fragment reads per MFMA: 1.5 -> 1.0 b128 (R6 ratio cut WITHOUT
//    R7's wave-count sacrifice: blocks stay 4-wave)
//  - A-staging bytes and barriers per MFMA halve
//  - LDS 32 KB -> 5 resident/CU; grid 1024 = exactly 4 blocks/CU ->
//    ALL blocks co-resident, no partial tail round (R8 ran 6+2)
// 16B slots XOR-swizzled by row&7 on both staging fetch and fragment reads.
// Epilogue stores: per-mi pointer chain + immediate offsets (cuts addr VALU).
// MODE 0: out_s = bernoulli(sigmoid(C + cvec)) fp8 {0,0x38}, row-stride KB
// MODE 1: atomicAdd(out_f, scale * sum(softplus(C + cvec)))
// MODE 2: out_f[row*N + col] = C   (raw fp32 store, no cvec)
// ---------------------------------------------------------------------------
template <int MODE>
__global__ __launch_bounds__(256, 4) void gemm_ep(
    const uint8_t* __restrict__ A, const uint8_t* __restrict__ Bt,
    const float* __restrict__ cvec, uint8_t* __restrict__ out_s,
    float* __restrict__ out_f, int N,
    uint32_t tag, float scale)
{
    constexpr int BM = 128, BN = 128, BK = 128;
    __shared__ __align__(16) uint8_t sA[BM * BK];   // 16 KB
    __shared__ __align__(16) uint8_t sB[BN * BK];   // 16 KB

    const int tid  = threadIdx.x;
    const int wave = tid >> 6;
    const int lane = tid & 63;
    // XCD-aware swizzle (1D grid = 128 m-blocks * n_blocks)
    const int bid   = blockIdx.x;
    const int m_idx = ((bid & 7) << 4) | ((bid >> 3) & 15);
    const int n_idx = bid >> 7;
    const int m0 = m_idx * BM;
    const int n0 = n_idx * BN;
    const int wr = (wave >> 1) * 64;   // wave row offset (0/64)
    const int wc = (wave & 1) * 64;    // wave col offset (0/64)
    const int cl   = lane & 15;
    const int quad = lane >> 4;

    // Staging: 32 chunks of (8 rows x 128 B): A chunks 0..15, B chunks 16..31.
    // Wave w loads chunks [8w, 8w+8). Lane covers row lane>>3, slot swizzled.
    const int lrow8 = lane >> 3;
    const int lcol  = ((lane & 7) ^ lrow8) << 4;
    const uint8_t* gp[8];
    uint8_t*       lp[8];
#pragma unroll
    for (int i = 0; i < 8; ++i) {
        int c = wave * 8 + i;
        if (c < 16) {
            gp[i] = A + (size_t)(m0 + c * 8 + lrow8) * KB + lcol;
            lp[i] = sA + c * 8 * BK;
        } else {
            gp[i] = Bt + (size_t)(n0 + (c - 16) * 8 + lrow8) * KB + lcol;
            lp[i] = sB + (c - 16) * 8 * BK;
        }
    }

    f32x4 acc[4][4] = {};
    union F8 { int4 h[2]; v8i v; };
    const int xr = cl & 7;
    const int p0 = ((2 * quad) ^ xr) << 4;
    const int p1 = ((2 * quad + 1) ^ xr) << 4;

    for (int kt = 0; kt < KB; kt += BK) {
#pragma unroll
        for (int i = 0; i < 8; ++i) load_lds16(gp[i] + kt, lp[i]);
        __syncthreads();

        v8i af[4];
#pragma unroll
        for (int mi = 0; mi < 4; ++mi) {
            const uint8_t* rp = sA + (wr + mi * 16 + cl) * BK;
            F8 f; f.h[0] = *(const int4*)(rp + p0); f.h[1] = *(const int4*)(rp + p1);
            af[mi] = f.v;
        }
#pragma unroll
        for (int ni = 0; ni < 4; ++ni) {
            const uint8_t* rp = sB + (wc + ni * 16 + cl) * BK;
            F8 fb; fb.h[0] = *(const int4*)(rp + p0); fb.h[1] = *(const int4*)(rp + p1);
#pragma unroll
            for (int mi = 0; mi < 4; ++mi)
                acc[mi][ni] = __builtin_amdgcn_mfma_scale_f32_16x16x128_f8f6f4(
                    af[mi], fb.v, acc[mi][ni],
                    0, 0, 0, 0x7F7F7F7F, 0, 0x7F7F7F7F);
        }
        __syncthreads();
    }

    // Epilogue. C/D layout: col = lane&15, row = quad*4 + reg (per 16x16 tile)
    const int row_base = m0 + wr + quad * 4;
    const int col_base = n0 + wc + cl;

    if (MODE == 0) {
        const uint32_t tagmix = tag * 0x85EBCA6Bu + 0xC2B2AE35u;
        uint32_t s = hash32((uint32_t)(bid * 256 + tid), tagmix);  // LCG seed
        float ccv[4];
#pragma unroll
        for (int ni = 0; ni < 4; ++ni)
            ccv[ni] = cvec[col_base + ni * 16] * NEG_L2E;
        uint8_t* prow = out_s + (size_t)row_base * KB + col_base;
#pragma unroll
        for (int mi = 0; mi < 4; ++mi) {
#pragma unroll
            for (int ni = 0; ni < 4; ++ni) {
#pragma unroll
                for (int r = 0; r < 4; ++r) {
                    // u < sigmoid(x)  <=>  u16 + u16*e^-x < 65536
                    float t = fmaf(acc[mi][ni][r], NEG_L2E, ccv[ni]);
                    float e = __builtin_amdgcn_exp2f(t);
                    s = s * 1664525u + 1013904223u;
                    float uf = (float)(s >> 16);
                    float prod = fmaf(uf, e, uf);
                    prow[r * KB + ni * 16] =
                        (prod < 65536.0f) ? (uint8_t)FP8_ONE : (uint8_t)0;
                }
            }
            prow += 16 * KB;
        }
    } else if (MODE == 1) {
        float cv[4];
#pragma unroll
        for (int ni = 0; ni < 4; ++ni) cv[ni] = cvec[col_base + ni * 16];
        float local = 0.0f;
#pragma unroll
        for (int mi = 0; mi < 4; ++mi)
#pragma unroll
            for (int ni = 0; ni < 4; ++ni)
#pragma unroll
                for (int r = 0; r < 4; ++r)
                    local += softplus_f(acc[mi][ni][r] + cv[ni]);
        local *= scale;
        for (int off = 32; off > 0; off >>= 1)
            local += __shfl_down(local, off, 64);
        __shared__ float wsum[4];
        if (lane == 0) wsum[wave] = local;
        __syncthreads();
        if (tid == 0)
            atomicAdd(out_f, wsum[0] + wsum[1] + wsum[2] + wsum[3]);
    } else {
#pragma unroll
        for (int mi = 0; mi < 4; ++mi)
#pragma unroll
            for (int ni = 0; ni < 4; ++ni)
#pragma unroll
                for (int r = 0; r < 4; ++r) {
                    int row = row_base + mi * 16 + r;
                    int col = col_base + ni * 16;
                    out_f[(size_t)row * N + col] = acc[mi][ni][r];
                }
    }
}

// ---------------------------------------------------------------------------
// W (VxH fp32) -> fp8 B-operands (row stride KB):
//   Btv[n][k] = W[n][k]  (v-GEMM)    Bth[n][k] = W[k][n]  (h-GEMM)
// ---------------------------------------------------------------------------
__global__ void wpack_kernel(const float* __restrict__ W,
                             uint8_t* __restrict__ Btv, uint8_t* __restrict__ Bth) {
    __shared__ float tile[32][33];
    int bx = blockIdx.x * 32, by = blockIdx.y * 32;
    int tx = threadIdx.x & 31, ty = threadIdx.x >> 5;
#pragma unroll
    for (int r = ty; r < 32; r += 8) {
        float v = W[(size_t)(by + r) * H_DIM + bx + tx];
        Btv[(size_t)(by + r) * KB + bx + tx] = f2fp8(v);
        tile[r][tx] = v;
    }
    __syncthreads();
#pragma unroll
    for (int r = ty; r < 32; r += 8)
        Bth[(size_t)(bx + r) * KB + by + tx] = f2fp8(tile[tx][r]);
}

// Tail cols [1024,1152) of Btv/Bth: rank-64 modulation factors + zero pad.
// Also fills BtP (the bdot-replacement B operand, 128 rows x KB):
//   BtP[k'][j] = Whb[k'][j] (k'<64), BtP[64][j] = bhat[j], rows 65..127 = 0
__global__ void wtail_kernel(const float* __restrict__ W2, const float* __restrict__ b,
                             const float* __restrict__ c, const float* __restrict__ b2,
                             uint8_t* __restrict__ Btv, uint8_t* __restrict__ Bth,
                             uint8_t* __restrict__ BtP) {
    int gid = blockIdx.x * 256 + threadIdx.x;   // 1024 * 128
    int n = gid >> 7, kp = gid & 127;
    if (kp < 64) {
        float wc = W2[(size_t)kp * P_COLS + 2048 + n] * c[n] + W2[(size_t)kp * P_COLS + 3072 + n];
        float wb = W2[(size_t)kp * P_COLS + n] * b[n]        + W2[(size_t)kp * P_COLS + 1024 + n];
        Bth[(size_t)n * KB + 1024 + kp] = f2fp8(wc);
        Btv[(size_t)n * KB + 1024 + kp] = f2fp8(wb);
        BtP[(size_t)kp * KB + n] = f2fp8(wb);
    } else {
        Bth[(size_t)n * KB + 1024 + kp] = 0;    // zero pad
        Btv[(size_t)n * KB + 1024 + kp] = 0;
        if (kp == 64) {
            float bh = b[n] * (1.0f + b2[n]) + b2[1024 + n];
            BtP[(size_t)64 * KB + n] = f2fp8(bh);
        } else {
            BtP[(size_t)kp * KB + n] = 0;
        }
    }
}

// Row-independent modulation constants (fp32, used as GEMM cvec):
__global__ void hatvec_kernel(const float* __restrict__ b, const float* __restrict__ c,
                              const float* __restrict__ b2,
                              float* __restrict__ bhat, float* __restrict__ chat) {
    int n = blockIdx.x * 256 + threadIdx.x;
    bhat[n] = b[n] * (1.0f + b2[n]) + b2[1024 + n];
    chat[n] = c[n] * (1.0f + b2[2048 + n]) + b2[3072 + n];
}

// h1 = tanh(cond @ W1 + b1); fp32 h1f + fp8 copies into tail cols of buffers.
__global__ void h1_kernel(const float* __restrict__ cond, const float* __restrict__ W1,
                          const float* __restrict__ b1, float* __restrict__ h1f,
                          uint8_t* __restrict__ vbuf, uint8_t* __restrict__ hbuf,
                          uint8_t* __restrict__ vdbuf) {
    int row = blockIdx.x * 4 + (threadIdx.x >> 6);
    int j   = threadIdx.x & 63;
    const float* cr = cond + (size_t)row * C_DIM;
    float s = b1[j];
#pragma unroll 8
    for (int k = 0; k < C_DIM; ++k) s = fmaf(cr[k], W1[k * 64 + j], s);
    float t = tanhf(s);
    h1f[(size_t)row * 64 + j] = t;
    size_t o = (size_t)row * KB + 1024 + j;
    uint8_t tb = f2fp8(t);
    vbuf[o] = tb; hbuf[o] = tb; vdbuf[o] = tb;
}

// v_start ~ Bern(0.5) into vbuf cols [0,1024)
__global__ void initv_kernel(uint8_t* __restrict__ v, uint32_t tag) {
    uint32_t g = (blockIdx.x * 256 + threadIdx.x) * 4;
    uint32_t row = g >> 10, col = g & 1023;
    uint32_t tagmix = tag * 0x85EBCA6Bu + 0xC2B2AE35u;
    uint32_t w = 0;
#pragma unroll
    for (int e = 0; e < 4; ++e)
        if (hash32(g + e, tagmix) & 0x80000000u)
            w |= (uint32_t)FP8_ONE << (8 * e);
    *(uint32_t*)(v + (size_t)row * KB + col) = w;
}

// v_data (fp32 0/1) -> vdbuf cols [0,1024), fp8 exact
__global__ void cast_kernel(const float* __restrict__ src, uint8_t* __restrict__ dst) {
    uint32_t g = (blockIdx.x * 256 + threadIdx.x) * 4;
    uint32_t row = g >> 10, col = g & 1023;
    f32x4 s = *(const f32x4*)(src + g);
    uint32_t w = 0;
#pragma unroll
    for (int e = 0; e < 4; ++e)
        if (s[e] >= 0.5f) w |= (uint32_t)FP8_ONE << (8 * e);
    *(uint32_t*)(dst + (size_t)row * KB + col) = w;
}

// T = vm - vd in fp8, written IN-PLACE over vd (tails cancel to exact 0).
__global__ void tdiff_kernel(uint8_t* __restrict__ vd, const uint8_t* __restrict__ vm) {
    size_t g = ((size_t)blockIdx.x * 256 + threadIdx.x) * 4;
    uint32_t a = *(const uint32_t*)(vm + g);
    uint32_t d = *(const uint32_t*)(vd + g);
    uint32_t t = 0;
#pragma unroll
    for (int e = 0; e < 4; ++e) {
        uint32_t vb = (a >> (8 * e)) & 0xFF, db = (d >> (8 * e)) & 0xFF;
        if (vb != db) t |= (vb ? (uint32_t)FP8_ONE : (uint32_t)FP8_NEG1) << (8 * e);
    }
    *(uint32_t*)(vd + g) = t;
}

// out += scale * sum_i [ P[i][64] + sum_k h1f[i][k] * P[i][k] ]
__global__ __launch_bounds__(256) void preduce_kernel(
    const float* __restrict__ P, const float* __restrict__ h1f,
    float* __restrict__ out, float scale) {
    int row = blockIdx.x * 256 + threadIdx.x;
    const f32x4* pr = (const f32x4*)(P + (size_t)row * 128);
    const f32x4* hr = (const f32x4*)(h1f + (size_t)row * 64);
    float local = P[(size_t)row * 128 + 64];
#pragma unroll
    for (int q = 0; q < 16; ++q) {
        f32x4 pv = pr[q], hv = hr[q];
#pragma unroll
        for (int e = 0; e < 4; ++e) local = fmaf(hv[e], pv[e], local);
    }
    local *= scale;
    for (int off = 32; off > 0; off >>= 1)
        local += __shfl_down(local, off, 64);
    __shared__ float wsum[4];
    int lane = threadIdx.x & 63, wave = threadIdx.x >> 6;
    if (lane == 0) wsum[wave] = local;
    __syncthreads();
    if (threadIdx.x == 0)
        atomicAdd(out, wsum[0] + wsum[1] + wsum[2] + wsum[3]);
}

// ---------------------------------------------------------------------------
extern "C" void kernel_launch(void* const* d_in, const int* in_sizes, int n_in,
                              void* d_out, int out_size, void* d_ws, size_t ws_size,
                              hipStream_t stream) {
    (void)in_sizes; (void)n_in; (void)out_size; (void)ws_size;
    const float* v_data = (const float*)d_in[0];
    const float* cond   = (const float*)d_in[1];
    const float* W      = (const float*)d_in[2];
    const float* b      = (const float*)d_in[3];
    const float* c      = (const float*)d_in[4];
    const float* W1     = (const float*)d_in[5];
    const float* b1     = (const float*)d_in[6];
    const float* W2     = (const float*)d_in[7];
    const float* b2     = (const float*)d_in[8];
    float* out = (float*)d_out;
    char*  ws  = (char*)d_ws;

    const size_t MB = 1024 * 1024;
    uint8_t* Btv  = (uint8_t*)(ws + 0 * MB);    // 1024 x KB fp8
    uint8_t* Bth  = (uint8_t*)(ws + 2 * MB);    // 1024 x KB fp8
    uint8_t* BtP  = (uint8_t*)(ws + 4 * MB);    // 128 x KB fp8 (144 KB)
    float*   h1f  = (float*)  (ws + 5 * MB);    // B x 64 fp32 (4 MB)
    float*   bhat = (float*)  (ws + 9 * MB);
    float*   chat = (float*)  (ws + 10 * MB);
    float*   Pbuf = (float*)  (ws + 11 * MB);   // B x 128 fp32 (8 MB)
    uint8_t* vbuf = (uint8_t*)(ws + 20 * MB);   // B x KB fp8 (18.9 MB)
    uint8_t* hbuf = (uint8_t*)(ws + 40 * MB);
    uint8_t* vdbuf= (uint8_t*)(ws + 60 * MB);
    // total ~79 MB

    hipMemsetAsync(d_out, 0, sizeof(float), stream);
    hipMemsetAsync(BtP, 0, (size_t)128 * KB, stream);  // tail cols + zero rows

    h1_kernel<<<B_ROWS / 4, 256, 0, stream>>>(cond, W1, b1, h1f, vbuf, hbuf, vdbuf);
    wpack_kernel<<<dim3(32, 32), 256, 0, stream>>>(W, Btv, Bth);
    wtail_kernel<<<(1024 * 128) / 256, 256, 0, stream>>>(W2, b, c, b2, Btv, Bth, BtP);
    hatvec_kernel<<<4, 256, 0, stream>>>(b, c, b2, bhat, chat);
    initv_kernel<<<(B_ROWS * 1024) / 1024, 256, 0, stream>>>(vbuf, 7u);
    cast_kernel<<<(B_ROWS * 1024) / 1024, 256, 0, stream>>>(v_data, vdbuf);

    const int ggrid = 1024;               // 128 m-blocks x 8 n-blocks, 1D+swizzle
    const float invB = 1.0f / (float)B_ROWS;

    for (int k = 0; k < K_STEPS; ++k) {
        gemm_ep<0><<<ggrid, 256, 0, stream>>>(vbuf, Bth, chat, hbuf, nullptr,
                                              H_DIM, 100u + 2u * (uint32_t)k, 0.0f);
        gemm_ep<0><<<ggrid, 256, 0, stream>>>(hbuf, Btv, bhat, vbuf, nullptr,
                                              V_DIM, 101u + 2u * (uint32_t)k, 0.0f);
    }

    // loss*B = sum softplus(vm@W + c_mod) - sum softplus(vd@W + c_mod)
    //          + sum (vm - vd)*b_mod      (rank-64 factored, GEMM-shaped)
    gemm_ep<1><<<ggrid, 256, 0, stream>>>(vbuf, Bth, chat, nullptr, out,
                                          H_DIM, 0u, invB);
    gemm_ep<1><<<ggrid, 256, 0, stream>>>(vdbuf, Bth, chat, nullptr, out,
                                          H_DIM, 1u, -invB);
    tdiff_kernel<<<(B_ROWS * KB) / 1024, 256, 0, stream>>>(vdbuf, vbuf);
    gemm_ep<2><<<128, 256, 0, stream>>>(vdbuf, BtP, nullptr, nullptr, Pbuf,
                                        128, 0u, 0.0f);
    preduce_kernel<<<B_ROWS / 256, 256, 0, stream>>>(Pbuf, h1f, out, invB);
}

// Round 11
// 1561.662 us; speedup vs baseline: 1.7103x; 1.3008x over previous
//
#include <hip/hip_runtime.h>
#include <stdint.h>

// Problem constants (match reference)
#define B_ROWS 16384
#define V_DIM  1024
#define H_DIM  1024
#define KB     1152   // padded K: 1024 state + 64 h1-tail + 64 ZERO pad (mult of 128)
#define C_DIM  64
#define P_COLS 4096   // 2*(V+H)
#define K_STEPS 25

#define FP8_ONE 0x38  // e4m3fn 1.0
#define FP8_NEG1 0xB8 // e4m3fn -1.0

typedef float f32x4 __attribute__((ext_vector_type(4)));
typedef int   v8i   __attribute__((ext_vector_type(8)));

// ---------------------------------------------------------------------------
// RNG. hash32 (lowbias32) seeds a per-thread LCG; epilogue draws are LCG
// high-16 bits. Deterministic per (thread, tag); loss is RNG-invariant
// (R1-R10: absmax == fp8-quantization error only).
// ---------------------------------------------------------------------------
__device__ __forceinline__ uint32_t hash32(uint32_t idx, uint32_t tagmix) {
    uint32_t x = idx * 0x9E3779B9u ^ tagmix;
    x ^= x >> 16; x *= 0x7FEB352Du;
    x ^= x >> 15; x *= 0x846CA68Bu;
    x ^= x >> 16;
    return x;
}

// async global->LDS, 16B per lane. LDS dst = wave-uniform base + lane*16.
__device__ __forceinline__ void load_lds16(const void* g, void* l) {
    __builtin_amdgcn_global_load_lds(
        (__attribute__((address_space(1))) void*)(uintptr_t)(g),
        (__attribute__((address_space(3))) void*)(l),
        16, 0, 0);
}

__device__ __forceinline__ float softplus_f(float x) {
    return fmaxf(x, 0.0f) + log1pf(__expf(-fabsf(x)));
}

__device__ __forceinline__ uint8_t f2fp8(float x) {
    int p = __builtin_amdgcn_cvt_pk_fp8_f32(x, 0.0f, 0, false);
    return (uint8_t)(p & 0xFF);
}

#define NEG_L2E (-1.4426950408889634f)

// ---------------------------------------------------------------------------
// fp8 GEMM C = A (MxKB) * Bt^T (Bt NxKB row-major), K fixed = KB, via
// mfma_scale_f32_16x16x128_f8f6f4 with unit scales.
// R11 = R8 EXACTLY (the measured optimum of the tile space: 256 thr, 4 waves
// of 64x32, BM=128 x BN=64 x BK=128, B in LDS, XCD swizzle, LCG epilogue,
// launch_bounds(256,5) -> VGPR 48, 6 blocks/CU) + zero-risk micro-opts:
//  (1) K compile-time -> kt loop fully unrolled, staging offsets = immediates
//      (R8 is VALU-issue-bound: VALUBusy 83%)
//  (2) MODE0 epilogue: pointer-chain stores w/ immediate offsets + fmaf form
// Tile-space map (measured): R7 fewer-waves ✗, R9 B-from-global ✗ (barrier-
// serialized L2 latency), R10 4x4 acc ✗ (VGPR spills, WRITE_SIZE 30 MB).
// 16B slots XOR-swizzled by row&7 on both staging fetch and fragment reads.
// MODE 0: out_s = bernoulli(sigmoid(C + cvec)) fp8 {0,0x38}, row-stride KB
// MODE 1: atomicAdd(out_f, scale * sum(softplus(C + cvec)))
// MODE 2: out_f[row*N + col] = C   (raw fp32 store, no cvec)
// ---------------------------------------------------------------------------
template <int MODE>
__global__ __launch_bounds__(256, 5) void gemm_ep(
    const uint8_t* __restrict__ A, const uint8_t* __restrict__ Bt,
    const float* __restrict__ cvec, uint8_t* __restrict__ out_s,
    float* __restrict__ out_f, int N,
    uint32_t tag, float scale)
{
    constexpr int BM = 128, BN = 64, BK = 128;
    __shared__ __align__(16) uint8_t sA[BM * BK];   // 16 KB
    __shared__ __align__(16) uint8_t sB[BN * BK];   //  8 KB

    const int tid  = threadIdx.x;
    const int wave = tid >> 6;
    const int lane = tid & 63;
    // XCD-aware swizzle (1D grid = 128 m-blocks * n_blocks)
    const int bid   = blockIdx.x;
    const int m_idx = ((bid & 7) << 4) | ((bid >> 3) & 15);
    const int n_idx = bid >> 7;
    const int m0 = m_idx * BM;
    const int n0 = n_idx * BN;
    const int wr = (wave >> 1) * 64;   // wave row offset (0/64)
    const int wc = (wave & 1) * 32;    // wave col offset (0/32)
    const int cl   = lane & 15;
    const int quad = lane >> 4;

    // Staging: 24 chunks of (8 rows x 128 B): A chunks 0..15, B chunks 16..23.
    // Wave w loads chunks [w*6, w*6+6). Lane covers row lane>>3, swizzled slot.
    const int lrow8 = lane >> 3;
    const int lcol  = ((lane & 7) ^ lrow8) << 4;
    const uint8_t* gp[6];
    uint8_t*       lp[6];
#pragma unroll
    for (int i = 0; i < 6; ++i) {
        int c = wave * 6 + i;
        if (c < 16) {
            gp[i] = A + (size_t)(m0 + c * 8 + lrow8) * KB + lcol;
            lp[i] = sA + c * 8 * BK;
        } else {
            gp[i] = Bt + (size_t)(n0 + (c - 16) * 8 + lrow8) * KB + lcol;
            lp[i] = sB + (c - 16) * 8 * BK;
        }
    }

    f32x4 acc[4][2] = {};
    union F8 { int4 h[2]; v8i v; };
    const int xr = cl & 7;
    const int p0 = ((2 * quad) ^ xr) << 4;
    const int p1 = ((2 * quad + 1) ^ xr) << 4;

#pragma unroll
    for (int kt = 0; kt < KB; kt += BK) {
#pragma unroll
        for (int i = 0; i < 6; ++i) load_lds16(gp[i] + kt, lp[i]);
        __syncthreads();

        v8i af[4], bfr[2];
#pragma unroll
        for (int mi = 0; mi < 4; ++mi) {
            const uint8_t* rp = sA + (wr + mi * 16 + cl) * BK;
            F8 f; f.h[0] = *(const int4*)(rp + p0); f.h[1] = *(const int4*)(rp + p1);
            af[mi] = f.v;
        }
#pragma unroll
        for (int ni = 0; ni < 2; ++ni) {
            const uint8_t* rp = sB + (wc + ni * 16 + cl) * BK;
            F8 f; f.h[0] = *(const int4*)(rp + p0); f.h[1] = *(const int4*)(rp + p1);
            bfr[ni] = f.v;
        }
#pragma unroll
        for (int mi = 0; mi < 4; ++mi) {
            acc[mi][0] = __builtin_amdgcn_mfma_scale_f32_16x16x128_f8f6f4(
                af[mi], bfr[0], acc[mi][0], 0, 0, 0, 0x7F7F7F7F, 0, 0x7F7F7F7F);
            acc[mi][1] = __builtin_amdgcn_mfma_scale_f32_16x16x128_f8f6f4(
                af[mi], bfr[1], acc[mi][1], 0, 0, 0, 0x7F7F7F7F, 0, 0x7F7F7F7F);
        }
        __syncthreads();
    }

    // Epilogue. C/D layout: col = lane&15, row = quad*4 + reg (per 16x16 tile)
    const int row_base = m0 + wr + quad * 4;
    const int col_base = n0 + wc + cl;

    if (MODE == 0) {
        const uint32_t tagmix = tag * 0x85EBCA6Bu + 0xC2B2AE35u;
        uint32_t s = hash32((uint32_t)(bid * 256 + tid), tagmix);  // LCG seed
        float ccv[2];
#pragma unroll
        for (int ni = 0; ni < 2; ++ni)
            ccv[ni] = cvec[col_base + ni * 16] * NEG_L2E;
        uint8_t* prow = out_s + (size_t)row_base * KB + col_base;
#pragma unroll
        for (int mi = 0; mi < 4; ++mi) {
#pragma unroll
            for (int ni = 0; ni < 2; ++ni) {
#pragma unroll
                for (int r = 0; r < 4; ++r) {
                    // u < sigmoid(x)  <=>  u16 + u16*e^-x < 65536
                    float t = fmaf(acc[mi][ni][r], NEG_L2E, ccv[ni]);
                    float e = __builtin_amdgcn_exp2f(t);
                    s = s * 1664525u + 1013904223u;
                    float uf = (float)(s >> 16);
                    float prod = fmaf(uf, e, uf);
                    prow[r * KB + ni * 16] =
                        (prod < 65536.0f) ? (uint8_t)FP8_ONE : (uint8_t)0;
                }
            }
            prow += 16 * KB;
        }
    } else if (MODE == 1) {
        float cv[2];
#pragma unroll
        for (int ni = 0; ni < 2; ++ni) cv[ni] = cvec[col_base + ni * 16];
        float local = 0.0f;
#pragma unroll
        for (int mi = 0; mi < 4; ++mi)
#pragma unroll
            for (int ni = 0; ni < 2; ++ni)
#pragma unroll
                for (int r = 0; r < 4; ++r)
                    local += softplus_f(acc[mi][ni][r] + cv[ni]);
        local *= scale;
        for (int off = 32; off > 0; off >>= 1)
            local += __shfl_down(local, off, 64);
        __shared__ float wsum[4];
        if (lane == 0) wsum[wave] = local;
        __syncthreads();
        if (tid == 0)
            atomicAdd(out_f, wsum[0] + wsum[1] + wsum[2] + wsum[3]);
    } else {
#pragma unroll
        for (int mi = 0; mi < 4; ++mi)
#pragma unroll
            for (int ni = 0; ni < 2; ++ni)
#pragma unroll
                for (int r = 0; r < 4; ++r) {
                    int row = row_base + mi * 16 + r;
                    int col = col_base + ni * 16;
                    out_f[(size_t)row * N + col] = acc[mi][ni][r];
                }
    }
}

// ---------------------------------------------------------------------------
// W (VxH fp32) -> fp8 B-operands (row stride KB):
//   Btv[n][k] = W[n][k]  (v-GEMM)    Bth[n][k] = W[k][n]  (h-GEMM)
// ---------------------------------------------------------------------------
__global__ void wpack_kernel(const float* __restrict__ W,
                             uint8_t* __restrict__ Btv, uint8_t* __restrict__ Bth) {
    __shared__ float tile[32][33];
    int bx = blockIdx.x * 32, by = blockIdx.y * 32;
    int tx = threadIdx.x & 31, ty = threadIdx.x >> 5;
#pragma unroll
    for (int r = ty; r < 32; r += 8) {
        float v = W[(size_t)(by + r) * H_DIM + bx + tx];
        Btv[(size_t)(by + r) * KB + bx + tx] = f2fp8(v);
        tile[r][tx] = v;
    }
    __syncthreads();
#pragma unroll
    for (int r = ty; r < 32; r += 8)
        Bth[(size_t)(bx + r) * KB + by + tx] = f2fp8(tile[tx][r]);
}

// Tail cols [1024,1152) of Btv/Bth: rank-64 modulation factors + zero pad.
// Also fills BtP (the bdot-replacement B operand, 128 rows x KB):
//   BtP[k'][j] = Whb[k'][j] (k'<64), BtP[64][j] = bhat[j], rows 65..127 = 0
__global__ void wtail_kernel(const float* __restrict__ W2, const float* __restrict__ b,
                             const float* __restrict__ c, const float* __restrict__ b2,
                             uint8_t* __restrict__ Btv, uint8_t* __restrict__ Bth,
                             uint8_t* __restrict__ BtP) {
    int gid = blockIdx.x * 256 + threadIdx.x;   // 1024 * 128
    int n = gid >> 7, kp = gid & 127;
    if (kp < 64) {
        float wc = W2[(size_t)kp * P_COLS + 2048 + n] * c[n] + W2[(size_t)kp * P_COLS + 3072 + n];
        float wb = W2[(size_t)kp * P_COLS + n] * b[n]        + W2[(size_t)kp * P_COLS + 1024 + n];
        Bth[(size_t)n * KB + 1024 + kp] = f2fp8(wc);
        Btv[(size_t)n * KB + 1024 + kp] = f2fp8(wb);
        BtP[(size_t)kp * KB + n] = f2fp8(wb);
    } else {
        Bth[(size_t)n * KB + 1024 + kp] = 0;    // zero pad
        Btv[(size_t)n * KB + 1024 + kp] = 0;
        if (kp == 64) {
            float bh = b[n] * (1.0f + b2[n]) + b2[1024 + n];
            BtP[(size_t)64 * KB + n] = f2fp8(bh);
        } else {
            BtP[(size_t)kp * KB + n] = 0;
        }
    }
}

// Row-independent modulation constants (fp32, used as GEMM cvec):
__global__ void hatvec_kernel(const float* __restrict__ b, const float* __restrict__ c,
                              const float* __restrict__ b2,
                              float* __restrict__ bhat, float* __restrict__ chat) {
    int n = blockIdx.x * 256 + threadIdx.x;
    bhat[n] = b[n] * (1.0f + b2[n]) + b2[1024 + n];
    chat[n] = c[n] * (1.0f + b2[2048 + n]) + b2[3072 + n];
}

// h1 = tanh(cond @ W1 + b1); fp32 h1f + fp8 copies into tail cols of buffers.
__global__ void h1_kernel(const float* __restrict__ cond, const float* __restrict__ W1,
                          const float* __restrict__ b1, float* __restrict__ h1f,
                          uint8_t* __restrict__ vbuf, uint8_t* __restrict__ hbuf,
                          uint8_t* __restrict__ vdbuf) {
    int row = blockIdx.x * 4 + (threadIdx.x >> 6);
    int j   = threadIdx.x & 63;
    const float* cr = cond + (size_t)row * C_DIM;
    float s = b1[j];
#pragma unroll 8
    for (int k = 0; k < C_DIM; ++k) s = fmaf(cr[k], W1[k * 64 + j], s);
    float t = tanhf(s);
    h1f[(size_t)row * 64 + j] = t;
    size_t o = (size_t)row * KB + 1024 + j;
    uint8_t tb = f2fp8(t);
    vbuf[o] = tb; hbuf[o] = tb; vdbuf[o] = tb;
}

// v_start ~ Bern(0.5) into vbuf cols [0,1024)
__global__ void initv_kernel(uint8_t* __restrict__ v, uint32_t tag) {
    uint32_t g = (blockIdx.x * 256 + threadIdx.x) * 4;
    uint32_t row = g >> 10, col = g & 1023;
    uint32_t tagmix = tag * 0x85EBCA6Bu + 0xC2B2AE35u;
    uint32_t w = 0;
#pragma unroll
    for (int e = 0; e < 4; ++e)
        if (hash32(g + e, tagmix) & 0x80000000u)
            w |= (uint32_t)FP8_ONE << (8 * e);
    *(uint32_t*)(v + (size_t)row * KB + col) = w;
}

// v_data (fp32 0/1) -> vdbuf cols [0,1024), fp8 exact
__global__ void cast_kernel(const float* __restrict__ src, uint8_t* __restrict__ dst) {
    uint32_t g = (blockIdx.x * 256 + threadIdx.x) * 4;
    uint32_t row = g >> 10, col = g & 1023;
    f32x4 s = *(const f32x4*)(src + g);
    uint32_t w = 0;
#pragma unroll
    for (int e = 0; e < 4; ++e)
        if (s[e] >= 0.5f) w |= (uint32_t)FP8_ONE << (8 * e);
    *(uint32_t*)(dst + (size_t)row * KB + col) = w;
}

// T = vm - vd in fp8, written IN-PLACE over vd (tails cancel to exact 0).
__global__ void tdiff_kernel(uint8_t* __restrict__ vd, const uint8_t* __restrict__ vm) {
    size_t g = ((size_t)blockIdx.x * 256 + threadIdx.x) * 4;
    uint32_t a = *(const uint32_t*)(vm + g);
    uint32_t d = *(const uint32_t*)(vd + g);
    uint32_t t = 0;
#pragma unroll
    for (int e = 0; e < 4; ++e) {
        uint32_t vb = (a >> (8 * e)) & 0xFF, db = (d >> (8 * e)) & 0xFF;
        if (vb != db) t |= (vb ? (uint32_t)FP8_ONE : (uint32_t)FP8_NEG1) << (8 * e);
    }
    *(uint32_t*)(vd + g) = t;
}

// out += scale * sum_i [ P[i][64] + sum_k h1f[i][k] * P[i][k] ]
__global__ __launch_bounds__(256) void preduce_kernel(
    const float* __restrict__ P, const float* __restrict__ h1f,
    float* __restrict__ out, float scale) {
    int row = blockIdx.x * 256 + threadIdx.x;
    const f32x4* pr = (const f32x4*)(P + (size_t)row * 128);
    const f32x4* hr = (const f32x4*)(h1f + (size_t)row * 64);
    float local = P[(size_t)row * 128 + 64];
#pragma unroll
    for (int q = 0; q < 16; ++q) {
        f32x4 pv = pr[q], hv = hr[q];
#pragma unroll
        for (int e = 0; e < 4; ++e) local = fmaf(hv[e], pv[e], local);
    }
    local *= scale;
    for (int off = 32; off > 0; off >>= 1)
        local += __shfl_down(local, off, 64);
    __shared__ float wsum[4];
    int lane = threadIdx.x & 63, wave = threadIdx.x >> 6;
    if (lane == 0) wsum[wave] = local;
    __syncthreads();
    if (threadIdx.x == 0)
        atomicAdd(out, wsum[0] + wsum[1] + wsum[2] + wsum[3]);
}

// ---------------------------------------------------------------------------
extern "C" void kernel_launch(void* const* d_in, const int* in_sizes, int n_in,
                              void* d_out, int out_size, void* d_ws, size_t ws_size,
                              hipStream_t stream) {
    (void)in_sizes; (void)n_in; (void)out_size; (void)ws_size;
    const float* v_data = (const float*)d_in[0];
    const float* cond   = (const float*)d_in[1];
    const float* W      = (const float*)d_in[2];
    const float* b      = (const float*)d_in[3];
    const float* c      = (const float*)d_in[4];
    const float* W1     = (const float*)d_in[5];
    const float* b1     = (const float*)d_in[6];
    const float* W2     = (const float*)d_in[7];
    const float* b2     = (const float*)d_in[8];
    float* out = (float*)d_out;
    char*  ws  = (char*)d_ws;

    const size_t MB = 1024 * 1024;
    uint8_t* Btv  = (uint8_t*)(ws + 0 * MB);    // 1024 x KB fp8
    uint8_t* Bth  = (uint8_t*)(ws + 2 * MB);    // 1024 x KB fp8
    uint8_t* BtP  = (uint8_t*)(ws + 4 * MB);    // 128 x KB fp8 (144 KB)
    float*   h1f  = (float*)  (ws + 5 * MB);    // B x 64 fp32 (4 MB)
    float*   bhat = (float*)  (ws + 9 * MB);
    float*   chat = (float*)  (ws + 10 * MB);
    float*   Pbuf = (float*)  (ws + 11 * MB);   // B x 128 fp32 (8 MB)
    uint8_t* vbuf = (uint8_t*)(ws + 20 * MB);   // B x KB fp8 (18.9 MB)
    uint8_t* hbuf = (uint8_t*)(ws + 40 * MB);
    uint8_t* vdbuf= (uint8_t*)(ws + 60 * MB);
    // total ~79 MB

    hipMemsetAsync(d_out, 0, sizeof(float), stream);
    hipMemsetAsync(BtP, 0, (size_t)128 * KB, stream);  // tail cols + zero rows

    h1_kernel<<<B_ROWS / 4, 256, 0, stream>>>(cond, W1, b1, h1f, vbuf, hbuf, vdbuf);
    wpack_kernel<<<dim3(32, 32), 256, 0, stream>>>(W, Btv, Bth);
    wtail_kernel<<<(1024 * 128) / 256, 256, 0, stream>>>(W2, b, c, b2, Btv, Bth, BtP);
    hatvec_kernel<<<4, 256, 0, stream>>>(b, c, b2, bhat, chat);
    initv_kernel<<<(B_ROWS * 1024) / 1024, 256, 0, stream>>>(vbuf, 7u);
    cast_kernel<<<(B_ROWS * 1024) / 1024, 256, 0, stream>>>(v_data, vdbuf);

    const int ggrid = 2048;               // 128 m-blocks x 16 n-blocks, 1D+swizzle
    const float invB = 1.0f / (float)B_ROWS;

    for (int k = 0; k < K_STEPS; ++k) {
        gemm_ep<0><<<ggrid, 256, 0, stream>>>(vbuf, Bth, chat, hbuf, nullptr,
                                              H_DIM, 100u + 2u * (uint32_t)k, 0.0f);
        gemm_ep<0><<<ggrid, 256, 0, stream>>>(hbuf, Btv, bhat, vbuf, nullptr,
                                              V_DIM, 101u + 2u * (uint32_t)k, 0.0f);
    }

    // loss*B = sum softplus(vm@W + c_mod) - sum softplus(vd@W + c_mod)
    //          + sum (vm - vd)*b_mod      (rank-64 factored, GEMM-shaped)
    gemm_ep<1><<<ggrid, 256, 0, stream>>>(vbuf, Bth, chat, nullptr, out,
                                          H_DIM, 0u, invB);
    gemm_ep<1><<<ggrid, 256, 0, stream>>>(vdbuf, Bth, chat, nullptr, out,
                                          H_DIM, 1u, -invB);
    tdiff_kernel<<<(B_ROWS * KB) / 1024, 256, 0, stream>>>(vdbuf, vbuf);
    gemm_ep<2><<<256, 256, 0, stream>>>(vdbuf, BtP, nullptr, nullptr, Pbuf,
                                        128, 0u, 0.0f);
    preduce_kernel<<<B_ROWS / 256, 256, 0, stream>>>(Pbuf, h1f, out, invB);
}